// Round 2
// baseline (1539.264 us; speedup 1.0000x reference)
//
#include <hip/hip_runtime.h>

#define B_ 8192
#define D_ 1024
#define H_ 2048
#define E_ 16
#define G_ 256

typedef unsigned short u16;
typedef __attribute__((ext_vector_type(4))) float f32x4;
typedef __attribute__((ext_vector_type(8))) short bf16x8;
typedef __attribute__((ext_vector_type(4))) unsigned short u16x4;

// ---------- module-static scratch: no dependence on ws_size -----------------
// Every buffer is fully rewritten on every kernel_launch call.
__device__ u16   g_W1t[(size_t)E_ * H_ * D_];   // 64 MiB  (diag(elnw)@e_w1)^T
__device__ u16   g_W2t[(size_t)E_ * G_ * H_];   // 16 MiB  e_w2^T
__device__ u16   g_GW1t[(size_t)G_ * D_];       // 0.5 MiB (diag(glnw)@g_w1)^T
__device__ u16   g_xhat[(size_t)B_ * D_];       // 16 MiB  layernorm(x) bf16
__device__ u16   g_gh[(size_t)B_ * G_];         // 4 MiB   gating hidden
__device__ float g_b1part[4 * E_ * H_];
__device__ float g_b1p[E_ * H_];                // e_b1 + e_ln_b @ e_w1
__device__ float g_gb1part[4 * G_];
__device__ float g_gb1p[G_];                    // g_b1 + g_ln_b @ g_w1
__device__ float g_gate[(size_t)B_ * E_];       // softmax gate
__device__ float g_oep[(size_t)E_ * B_ * 2];    // per-expert gated partials

__device__ __forceinline__ u16 f2bf(float f) {
  unsigned int u = __float_as_uint(f);
  unsigned int r = (u + 0x7fffu + ((u >> 16) & 1u)) >> 16;
  return (u16)r;
}
__device__ __forceinline__ float bf2f(u16 u) {
  return __uint_as_float((unsigned int)u << 16);
}
__device__ __forceinline__ void gld16(const void* g, void* l) {
  __builtin_amdgcn_global_load_lds(
      (const __attribute__((address_space(1))) unsigned int*)g,
      (__attribute__((address_space(3))) unsigned int*)l, 16, 0, 0);
}

// ---------------- prep: batched transpose + row-scale + cast to bf16 --------
// src [z][R][C] f32 -> dst [z][C][R] bf16 ; optional scale[z][R] on src rows.
// which: 0 = g_W1t, 1 = g_W2t, 2 = g_GW1t
__global__ __launch_bounds__(256) void k_transpose_scale(
    const float* __restrict__ src, const float* __restrict__ scale,
    int which, int R, int C) {
  u16* dstb = (which == 0) ? g_W1t : (which == 1) ? g_W2t : g_GW1t;
  __shared__ float tile[32][33];
  int z = blockIdx.z;
  const float* s = src + (size_t)z * R * C;
  u16* d = dstb + (size_t)z * R * C;
  int c0 = blockIdx.x * 32, r0 = blockIdx.y * 32;
#pragma unroll
  for (int i = 0; i < 4; i++) {
    int r = r0 + threadIdx.y + i * 8;
    int c = c0 + threadIdx.x;
    float v = s[(size_t)r * C + c];
    if (scale) v *= scale[(size_t)z * R + r];
    tile[threadIdx.y + i * 8][threadIdx.x] = v;
  }
  __syncthreads();
#pragma unroll
  for (int i = 0; i < 4; i++) {
    int c = c0 + threadIdx.y + i * 8;
    int r = r0 + threadIdx.x;
    d[(size_t)c * R + r] = f2bf(tile[threadIdx.x][threadIdx.y + i * 8]);
  }
}

// ---------------- prep: partial[dc][z][N] = (dc==0 ? bias : 0) + lnb_chunk@W -
// which: 0 = g_b1part, 1 = g_gb1part
__global__ __launch_bounds__(256) void k_prep_bias(
    const float* __restrict__ W, const float* __restrict__ lnb,
    const float* __restrict__ bias, int which, int D, int N, int Z) {
  float* part = (which == 0) ? g_b1part : g_gb1part;
  int z = blockIdx.x;
  int n = blockIdx.y * 256 + threadIdx.x;
  int dc = blockIdx.z;
  int dlen = D / 4, d0 = dc * dlen;
  const float* Wb = W + (size_t)z * D * N;
  const float* lb = lnb + (size_t)z * D;
  float acc = (dc == 0) ? bias[(size_t)z * N + n] : 0.f;
  for (int d = d0; d < d0 + dlen; d++) acc += lb[d] * Wb[(size_t)d * N + n];
  part[((size_t)dc * Z + z) * N + n] = acc;
}

// which: 0 -> g_b1p (len E_*H_), 1 -> g_gb1p (len G_)
__global__ __launch_bounds__(256) void k_combine_bias(int which, int len) {
  const float* part = (which == 0) ? g_b1part : g_gb1part;
  float* out = (which == 0) ? g_b1p : g_gb1p;
  int i = blockIdx.x * 256 + threadIdx.x;
  if (i < len)
    out[i] = part[i] + part[len + i] + part[2 * len + i] + part[3 * len + i];
}

// ---------------- layernorm -> bf16 xhat ------------------------------------
__global__ __launch_bounds__(256) void k_layernorm(const float* __restrict__ x) {
  int row = blockIdx.x;
  int tid = threadIdx.x;
  const float4 v = ((const float4*)(x + (size_t)row * D_))[tid];
  float s1 = v.x + v.y + v.z + v.w;
  float s2 = v.x * v.x + v.y * v.y + v.z * v.z + v.w * v.w;
#pragma unroll
  for (int m = 1; m < 64; m <<= 1) {
    s1 += __shfl_xor(s1, m, 64);
    s2 += __shfl_xor(s2, m, 64);
  }
  __shared__ float red[8];
  int w = tid >> 6, l = tid & 63;
  if (l == 0) { red[w * 2] = s1; red[w * 2 + 1] = s2; }
  __syncthreads();
  s1 = red[0] + red[2] + red[4] + red[6];
  s2 = red[1] + red[3] + red[5] + red[7];
  float mu = s1 * (1.f / D_);
  float var = s2 * (1.f / D_) - mu * mu;
  float rs = rsqrtf(var + 1e-5f);
  u16x4 p;
  p.x = f2bf((v.x - mu) * rs);
  p.y = f2bf((v.y - mu) * rs);
  p.z = f2bf((v.z - mu) * rs);
  p.w = f2bf((v.w - mu) * rs);
  ((u16x4*)(g_xhat + (size_t)row * D_))[tid] = p;
}

// ---------------- gating GEMM: gh = relu(xhat @ GW1' + gb1') ----------------
// Tile 64x128, BK=64, 4 waves (each 64x32).
__global__ __launch_bounds__(256) void k_gating_gemm() {
  __shared__ alignas(16) char pool[8192 + 16384];
  u16* A_st = (u16*)pool;            // [64][64]
  u16* B_st = (u16*)(pool + 8192);   // [128][64]
  const int r0 = blockIdx.x * 64;
  const int n0 = blockIdx.y * 128;
  const int tid = threadIdx.x, l = tid & 63, w = tid >> 6;
  const int l15 = l & 15, l4 = l >> 4;
  const int srow = tid >> 3, sk8 = tid & 7;

  f32x4 zero4 = {0.f, 0.f, 0.f, 0.f};
  f32x4 acc[4][2];
#pragma unroll
  for (int i = 0; i < 4; i++)
#pragma unroll
    for (int j = 0; j < 2; j++) acc[i][j] = zero4;

  for (int s = 0; s < 16; s++) {
    __syncthreads();
#pragma unroll
    for (int r = 0; r < 2; r++) {
      int row = r * 32 + srow;
      gld16(g_xhat + (size_t)(r0 + row) * D_ + s * 64 + sk8 * 8,
            (char*)A_st + (r * 256 + (tid & 192)) * 16);
    }
#pragma unroll
    for (int r = 0; r < 4; r++) {
      int row = r * 32 + srow;
      gld16(g_GW1t + (size_t)(n0 + row) * D_ + s * 64 + sk8 * 8,
            (char*)B_st + (r * 256 + (tid & 192)) * 16);
    }
    __syncthreads();
#pragma unroll
    for (int t = 0; t < 2; t++) {
      bf16x8 af[4], bfr[2];
#pragma unroll
      for (int mi = 0; mi < 4; mi++)
        af[mi] = *(const bf16x8*)&A_st[(mi * 16 + l15) * 64 + t * 32 + l4 * 8];
#pragma unroll
      for (int ni = 0; ni < 2; ni++)
        bfr[ni] = *(const bf16x8*)&B_st[(w * 32 + ni * 16 + l15) * 64 + t * 32 + l4 * 8];
#pragma unroll
      for (int mi = 0; mi < 4; mi++)
#pragma unroll
        for (int ni = 0; ni < 2; ni++)
          acc[mi][ni] = __builtin_amdgcn_mfma_f32_16x16x32_bf16(
              af[mi], bfr[ni], acc[mi][ni], 0, 0, 0);
    }
  }
#pragma unroll
  for (int ni = 0; ni < 2; ni++) {
    int n = n0 + w * 32 + ni * 16 + l15;
    float bv = g_gb1p[n];
#pragma unroll
    for (int mi = 0; mi < 4; mi++)
#pragma unroll
      for (int q = 0; q < 4; q++) {
        int row = r0 + mi * 16 + l4 * 4 + q;
        g_gh[(size_t)row * G_ + n] = f2bf(fmaxf(acc[mi][ni][q] + bv, 0.f));
      }
  }
}

// ---------------- gating softmax: gate = softmax(gh @ g_w2 + g_b2) ----------
__global__ __launch_bounds__(256) void k_gating_softmax(
    const float* __restrict__ gw2, const float* __restrict__ gb2) {
  int tid = threadIdx.x;
  int rl = tid >> 4, j = tid & 15;
  int row = blockIdx.x * 16 + rl;
  const u16* gr = g_gh + (size_t)row * G_;
  float acc = gb2[j];
  for (int k = 0; k < G_; k++) acc += bf2f(gr[k]) * gw2[k * 16 + j];
  float m = acc;
#pragma unroll
  for (int mm = 1; mm < 16; mm <<= 1) m = fmaxf(m, __shfl_xor(m, mm, 64));
  float e = expf(acc - m);
  float s = e;
#pragma unroll
  for (int mm = 1; mm < 16; mm <<= 1) s += __shfl_xor(s, mm, 64);
  g_gate[(size_t)row * 16 + j] = e / s;
}

// ---------------- fused expert chain ----------------------------------------
// Per (expert, 128-row block): GEMM1 (K=1024) -> relu tile in LDS -> GEMM2
// accumulates h2[128][256] in registers -> epilogue folds W3/b3/gate.
// XCD affinity: 64 blocks/XCD co-resident => all row-blocks of one expert
// share that expert's 4 MiB W1 slice in the XCD-local L2.
__global__ __launch_bounds__(256, 2) void k_chain(
    const float* __restrict__ eb2,  // [E_][G_]
    const float* __restrict__ w3,   // [E_][G_][2]
    const float* __restrict__ b3)   // [E_][2]
{
  constexpr int BM = 128, NT = 128, BK = 64;
  constexpr int C1LD = NT + 8;  // 272B row stride = 17*16B: 16B-aligned, ~2-way
  __shared__ alignas(16) char pool[32768 + BM * C1LD * 2 + 2 * BM * 2 * 4];
  u16* A_st = (u16*)pool;                        // [128][64]
  u16* B_st = (u16*)(pool + 16384);              // [128][64]
  u16* C1 = (u16*)(pool + 32768);                // [128][136]
  float* oeac = (float*)(pool + 32768 + BM * C1LD * 2);  // [2][128][2]

  // XCD-affinity remap (grid = 1024 linear blocks, round-robin %8 -> XCD)
  const int wg = blockIdx.x;
  const int xcd = wg & 7;
  const int idx = wg >> 3;            // 0..127
  const int e = xcd * 2 + (idx >> 6); // experts {2*xcd, 2*xcd+1}
  const int r0 = (idx & 63) * BM;

  const int tid = threadIdx.x;
  const int l = tid & 63, w = tid >> 6;
  const int wr = w >> 1, wc = w & 1;  // 2x2 wave grid
  const int l15 = l & 15, l4 = l >> 4;
  const int srow = tid >> 3, sk8 = tid & 7;

  const u16* W1e = g_W1t + (size_t)e * H_ * D_;
  const u16* W2e = g_W2t + (size_t)e * G_ * H_;

  f32x4 zero4 = {0.f, 0.f, 0.f, 0.f};
  f32x4 acc2[4][8];
#pragma unroll
  for (int i = 0; i < 4; i++)
#pragma unroll
    for (int j = 0; j < 8; j++) acc2[i][j] = zero4;

  for (int kk = 0; kk < H_ / NT; kk++) {
    f32x4 acc1[4][4];
#pragma unroll
    for (int i = 0; i < 4; i++)
#pragma unroll
      for (int j = 0; j < 4; j++) acc1[i][j] = zero4;

    // ---- GEMM1: C1 = xhat[rows] @ W1'[:, kk*128 .. +128], K = 1024 ----
    for (int s = 0; s < D_ / BK; s++) {
      __syncthreads();
#pragma unroll
      for (int r = 0; r < 4; r++) {
        int row = r * 32 + srow;
        gld16(g_xhat + (size_t)(r0 + row) * D_ + s * BK + sk8 * 8,
              (char*)A_st + (r * 256 + (tid & 192)) * 16);
      }
#pragma unroll
      for (int r = 0; r < 4; r++) {
        int row = r * 32 + srow;
        gld16(W1e + (size_t)(kk * NT + row) * D_ + s * BK + sk8 * 8,
              (char*)B_st + (r * 256 + (tid & 192)) * 16);
      }
      __syncthreads();
#pragma unroll
      for (int t = 0; t < 2; t++) {
        bf16x8 af[4], bfr[4];
#pragma unroll
        for (int mi = 0; mi < 4; mi++)
          af[mi] = *(const bf16x8*)&A_st[(wr * 64 + mi * 16 + l15) * BK + t * 32 + l4 * 8];
#pragma unroll
        for (int ni = 0; ni < 4; ni++)
          bfr[ni] = *(const bf16x8*)&B_st[(wc * 64 + ni * 16 + l15) * BK + t * 32 + l4 * 8];
#pragma unroll
        for (int mi = 0; mi < 4; mi++)
#pragma unroll
          for (int ni = 0; ni < 4; ni++)
            acc1[mi][ni] = __builtin_amdgcn_mfma_f32_16x16x32_bf16(
                af[mi], bfr[ni], acc1[mi][ni], 0, 0, 0);
      }
    }
    // ---- bias + relu -> C1 (bf16, padded LDS) ----
    float bn[4];
#pragma unroll
    for (int ni = 0; ni < 4; ni++)
      bn[ni] = g_b1p[e * H_ + kk * NT + wc * 64 + ni * 16 + l15];
#pragma unroll
    for (int mi = 0; mi < 4; mi++)
#pragma unroll
      for (int ni = 0; ni < 4; ni++)
#pragma unroll
        for (int q = 0; q < 4; q++) {
          float v = fmaxf(acc1[mi][ni][q] + bn[ni], 0.f);
          C1[(wr * 64 + mi * 16 + l4 * 4 + q) * C1LD + wc * 64 + ni * 16 + l15] = f2bf(v);
        }
    __syncthreads();  // C1 visible; stage buffers now free for B2

    // ---- GEMM2: acc2 += relu-tile @ W2[kk*128 .. +128, :], K = 128 ----
#pragma unroll
    for (int k2 = 0; k2 < 2; k2++) {
#pragma unroll
      for (int r = 0; r < 8; r++) {
        int grow = r * 32 + srow;
        gld16(W2e + (size_t)grow * H_ + kk * NT + k2 * 64 + sk8 * 8,
              pool + (r * 256 + (tid & 192)) * 16);
      }
      __syncthreads();
      const u16* B2 = (const u16*)pool;  // [256][64]
#pragma unroll
      for (int t = 0; t < 2; t++) {
        bf16x8 a2[4];
#pragma unroll
        for (int mi = 0; mi < 4; mi++)
          a2[mi] = *(const bf16x8*)&C1[(wr * 64 + mi * 16 + l15) * C1LD + k2 * 64 + t * 32 + l4 * 8];
#pragma unroll
        for (int nj = 0; nj < 8; nj++) {
          bf16x8 b2 = *(const bf16x8*)&B2[(wc * 128 + nj * 16 + l15) * 64 + t * 32 + l4 * 8];
#pragma unroll
          for (int mi = 0; mi < 4; mi++)
            acc2[mi][nj] = __builtin_amdgcn_mfma_f32_16x16x32_bf16(
                a2[mi], b2, acc2[mi][nj], 0, 0, 0);
        }
      }
      __syncthreads();
    }
  }

  // ---- epilogue: oe = relu(h2 + b2) @ W3 ; oep = gate * (oe + b3) ----
  float w30[8], w31[8], bb[8];
#pragma unroll
  for (int nj = 0; nj < 8; nj++) {
    int g = wc * 128 + nj * 16 + l15;
    w30[nj] = w3[(e * G_ + g) * 2 + 0];
    w31[nj] = w3[(e * G_ + g) * 2 + 1];
    bb[nj] = eb2[e * G_ + g];
  }
#pragma unroll
  for (int mi = 0; mi < 4; mi++)
#pragma unroll
    for (int q = 0; q < 4; q++) {
      float s0 = 0.f, s1 = 0.f;
#pragma unroll
      for (int nj = 0; nj < 8; nj++) {
        float h = fmaxf(acc2[mi][nj][q] + bb[nj], 0.f);
        s0 += h * w30[nj];
        s1 += h * w31[nj];
      }
#pragma unroll
      for (int mm = 1; mm < 16; mm <<= 1) {
        s0 += __shfl_xor(s0, mm, 64);
        s1 += __shfl_xor(s1, mm, 64);
      }
      if (l15 == 0) {  // one writer per (wc, row): plain stores, no atomics
        int row = wr * 64 + mi * 16 + l4 * 4 + q;
        oeac[(wc * BM + row) * 2 + 0] = s0;
        oeac[(wc * BM + row) * 2 + 1] = s1;
      }
    }
  __syncthreads();
  if (tid < BM) {
    int row = tid;
    float gg = g_gate[(size_t)(r0 + row) * E_ + e];
    float o0 = oeac[row * 2 + 0] + oeac[(BM + row) * 2 + 0] + b3[e * 2 + 0];
    float o1 = oeac[row * 2 + 1] + oeac[(BM + row) * 2 + 1] + b3[e * 2 + 1];
    g_oep[((size_t)e * B_ + (r0 + row)) * 2 + 0] = gg * o0;
    g_oep[((size_t)e * B_ + (r0 + row)) * 2 + 1] = gg * o1;
  }
}

// ---------------- finalize: sum experts, split columns, softplus ------------
__global__ __launch_bounds__(256) void k_finalize(float* __restrict__ out) {
  int i = blockIdx.x * 256 + threadIdx.x;
  float m = 0.f, v = 0.f;
#pragma unroll
  for (int e = 0; e < E_; e++) {
    m += g_oep[((size_t)e * B_ + i) * 2 + 0];
    v += g_oep[((size_t)e * B_ + i) * 2 + 1];
  }
  float sp = (v > 20.f) ? v : log1pf(expf(v));
  out[i] = m;
  out[B_ + i] = sp + 1e-6f;
}

// ---------------------------------------------------------------------------
extern "C" void kernel_launch(void* const* d_in, const int* in_sizes, int n_in,
                              void* d_out, int out_size, void* d_ws, size_t ws_size,
                              hipStream_t stream) {
  const float* x    = (const float*)d_in[0];
  const float* glnw = (const float*)d_in[1];
  const float* glnb = (const float*)d_in[2];
  const float* gw1  = (const float*)d_in[3];
  const float* gb1  = (const float*)d_in[4];
  const float* gw2  = (const float*)d_in[5];
  const float* gb2  = (const float*)d_in[6];
  const float* elnw = (const float*)d_in[7];
  const float* elnb = (const float*)d_in[8];
  const float* ew1  = (const float*)d_in[9];
  const float* eb1  = (const float*)d_in[10];
  const float* ew2  = (const float*)d_in[11];
  const float* eb2  = (const float*)d_in[12];
  const float* ew3  = (const float*)d_in[13];
  const float* eb3  = (const float*)d_in[14];
  float* out = (float*)d_out;
  (void)d_ws; (void)ws_size;

  dim3 tb(32, 8);
  // g_W1t[e] = (diag(e_ln_w[e]) @ e_w1[e])^T : src [16][1024][2048]
  k_transpose_scale<<<dim3(H_ / 32, D_ / 32, E_), tb, 0, stream>>>(ew1, elnw, 0, D_, H_);
  // g_W2t[e] = e_w2[e]^T : src [16][2048][256]
  k_transpose_scale<<<dim3(G_ / 32, H_ / 32, E_), tb, 0, stream>>>(ew2, nullptr, 1, H_, G_);
  // g_GW1t = (diag(g_ln_w) @ g_w1)^T : src [1024][256]
  k_transpose_scale<<<dim3(G_ / 32, D_ / 32, 1), tb, 0, stream>>>(gw1, glnw, 2, D_, G_);

  k_prep_bias<<<dim3(E_, H_ / 256, 4), 256, 0, stream>>>(ew1, elnb, eb1, 0, D_, H_, E_);
  k_prep_bias<<<dim3(1, 1, 4), 256, 0, stream>>>(gw1, glnb, gb1, 1, D_, G_, 1);
  k_combine_bias<<<(E_ * H_ + 255) / 256, 256, 0, stream>>>(0, E_ * H_);
  k_combine_bias<<<1, 256, 0, stream>>>(1, G_);

  k_layernorm<<<B_, 256, 0, stream>>>(x);
  k_gating_gemm<<<dim3(B_ / 64, G_ / 128), 256, 0, stream>>>();
  k_gating_softmax<<<B_ / 16, 256, 0, stream>>>(gw2, gb2);

  k_chain<<<dim3(B_ / 128 * E_), 256, 0, stream>>>(eb2, ew3, eb3);

  k_finalize<<<B_ / 256, 256, 0, stream>>>(out);
}

// Round 3
// 1341.477 us; speedup vs baseline: 1.1474x; 1.1474x over previous
//
#include <hip/hip_runtime.h>

#define B_ 8192
#define D_ 1024
#define H_ 2048
#define E_ 16
#define G_ 256

typedef unsigned short u16;
typedef __attribute__((ext_vector_type(4))) float f32x4;
typedef __attribute__((ext_vector_type(8))) short bf16x8;
typedef __attribute__((ext_vector_type(4))) unsigned short u16x4;

// ---------- module-static scratch: no dependence on ws_size -----------------
__device__ u16   g_W1t[(size_t)E_ * H_ * D_];   // 64 MiB  (diag(elnw)@e_w1)^T
__device__ u16   g_W2t[(size_t)E_ * G_ * H_];   // 16 MiB  e_w2^T
__device__ u16   g_GW1t[(size_t)G_ * D_];       // 0.5 MiB (diag(glnw)@g_w1)^T
__device__ u16   g_xhat[(size_t)B_ * D_];       // 16 MiB  layernorm(x) bf16
__device__ u16   g_gh[(size_t)B_ * G_];         // 4 MiB   gating hidden
__device__ float g_b1part[4 * E_ * H_];
__device__ float g_b1p[E_ * H_];
__device__ float g_gb1part[4 * G_];
__device__ float g_gb1p[G_];
__device__ float g_gate[(size_t)B_ * E_];
__device__ float g_oep[(size_t)E_ * B_ * 2];

__device__ __forceinline__ u16 f2bf(float f) {
  unsigned int u = __float_as_uint(f);
  unsigned int r = (u + 0x7fffu + ((u >> 16) & 1u)) >> 16;
  return (u16)r;
}
__device__ __forceinline__ float bf2f(u16 u) {
  return __uint_as_float((unsigned int)u << 16);
}
__device__ __forceinline__ void gld16(const void* g, void* l) {
  __builtin_amdgcn_global_load_lds(
      (const __attribute__((address_space(1))) unsigned int*)g,
      (__attribute__((address_space(3))) unsigned int*)l, 16, 0, 0);
}

// ---------------- prep: batched transpose + row-scale + cast to bf16 --------
__global__ __launch_bounds__(256) void k_transpose_scale(
    const float* __restrict__ src, const float* __restrict__ scale,
    int which, int R, int C) {
  u16* dstb = (which == 0) ? g_W1t : (which == 1) ? g_W2t : g_GW1t;
  __shared__ float tile[32][33];
  int z = blockIdx.z;
  const float* s = src + (size_t)z * R * C;
  u16* d = dstb + (size_t)z * R * C;
  int c0 = blockIdx.x * 32, r0 = blockIdx.y * 32;
#pragma unroll
  for (int i = 0; i < 4; i++) {
    int r = r0 + threadIdx.y + i * 8;
    int c = c0 + threadIdx.x;
    float v = s[(size_t)r * C + c];
    if (scale) v *= scale[(size_t)z * R + r];
    tile[threadIdx.y + i * 8][threadIdx.x] = v;
  }
  __syncthreads();
#pragma unroll
  for (int i = 0; i < 4; i++) {
    int c = c0 + threadIdx.y + i * 8;
    int r = r0 + threadIdx.x;
    d[(size_t)c * R + r] = f2bf(tile[threadIdx.x][threadIdx.y + i * 8]);
  }
}

// ---------------- prep: partial bias = (dc==0 ? bias : 0) + lnb_chunk @ W ---
__global__ __launch_bounds__(256) void k_prep_bias(
    const float* __restrict__ W, const float* __restrict__ lnb,
    const float* __restrict__ bias, int which, int D, int N, int Z) {
  float* part = (which == 0) ? g_b1part : g_gb1part;
  int z = blockIdx.x;
  int n = blockIdx.y * 256 + threadIdx.x;
  int dc = blockIdx.z;
  int dlen = D / 4, d0 = dc * dlen;
  const float* Wb = W + (size_t)z * D * N;
  const float* lb = lnb + (size_t)z * D;
  float acc = (dc == 0) ? bias[(size_t)z * N + n] : 0.f;
  for (int d = d0; d < d0 + dlen; d++) acc += lb[d] * Wb[(size_t)d * N + n];
  part[((size_t)dc * Z + z) * N + n] = acc;
}

__global__ __launch_bounds__(256) void k_combine_bias(int which, int len) {
  const float* part = (which == 0) ? g_b1part : g_gb1part;
  float* out = (which == 0) ? g_b1p : g_gb1p;
  int i = blockIdx.x * 256 + threadIdx.x;
  if (i < len)
    out[i] = part[i] + part[len + i] + part[2 * len + i] + part[3 * len + i];
}

// ---------------- layernorm -> bf16 xhat ------------------------------------
__global__ __launch_bounds__(256) void k_layernorm(const float* __restrict__ x) {
  int row = blockIdx.x;
  int tid = threadIdx.x;
  const float4 v = ((const float4*)(x + (size_t)row * D_))[tid];
  float s1 = v.x + v.y + v.z + v.w;
  float s2 = v.x * v.x + v.y * v.y + v.z * v.z + v.w * v.w;
#pragma unroll
  for (int m = 1; m < 64; m <<= 1) {
    s1 += __shfl_xor(s1, m, 64);
    s2 += __shfl_xor(s2, m, 64);
  }
  __shared__ float red[8];
  int w = tid >> 6, l = tid & 63;
  if (l == 0) { red[w * 2] = s1; red[w * 2 + 1] = s2; }
  __syncthreads();
  s1 = red[0] + red[2] + red[4] + red[6];
  s2 = red[1] + red[3] + red[5] + red[7];
  float mu = s1 * (1.f / D_);
  float var = s2 * (1.f / D_) - mu * mu;
  float rs = rsqrtf(var + 1e-5f);
  u16x4 p;
  p.x = f2bf((v.x - mu) * rs);
  p.y = f2bf((v.y - mu) * rs);
  p.z = f2bf((v.z - mu) * rs);
  p.w = f2bf((v.w - mu) * rs);
  ((u16x4*)(g_xhat + (size_t)row * D_))[tid] = p;
}

// ---------------- gating GEMM: gh = relu(xhat @ GW1' + gb1') ----------------
// Tile 64x128, BK=64, 4 waves. XOR-swizzled stage (both-sides, rule #21).
__global__ __launch_bounds__(256) void k_gating_gemm() {
  __shared__ alignas(16) char pool[8192 + 16384];
  u16* A_st = (u16*)pool;            // [64][64]
  u16* B_st = (u16*)(pool + 8192);   // [128][64]
  const int r0 = blockIdx.x * 64;
  const int n0 = blockIdx.y * 128;
  const int tid = threadIdx.x, l = tid & 63, w = tid >> 6;
  const int l15 = l & 15, l4 = l >> 4, lx = l15 & 7;
  const int srow = tid >> 3;
  const int sk8s = (tid & 7) ^ ((tid >> 3) & 7);  // swizzled source col

  f32x4 zero4 = {0.f, 0.f, 0.f, 0.f};
  f32x4 acc[4][2];
#pragma unroll
  for (int i = 0; i < 4; i++)
#pragma unroll
    for (int j = 0; j < 2; j++) acc[i][j] = zero4;

  for (int s = 0; s < 16; s++) {
    __syncthreads();
#pragma unroll
    for (int r = 0; r < 2; r++) {
      int row = r * 32 + srow;
      gld16(g_xhat + (size_t)(r0 + row) * D_ + s * 64 + sk8s * 8,
            (char*)A_st + (r * 256 + (tid & 192)) * 16);
    }
#pragma unroll
    for (int r = 0; r < 4; r++) {
      int row = r * 32 + srow;
      gld16(g_GW1t + (size_t)(n0 + row) * D_ + s * 64 + sk8s * 8,
            (char*)B_st + (r * 256 + (tid & 192)) * 16);
    }
    __syncthreads();
#pragma unroll
    for (int t = 0; t < 2; t++) {
      bf16x8 af[4], bfr[2];
#pragma unroll
      for (int mi = 0; mi < 4; mi++)
        af[mi] = *(const bf16x8*)&A_st[(mi * 16 + l15) * 64 + ((t * 4 + l4) ^ lx) * 8];
#pragma unroll
      for (int ni = 0; ni < 2; ni++)
        bfr[ni] = *(const bf16x8*)&B_st[(w * 32 + ni * 16 + l15) * 64 + ((t * 4 + l4) ^ lx) * 8];
#pragma unroll
      for (int mi = 0; mi < 4; mi++)
#pragma unroll
        for (int ni = 0; ni < 2; ni++)
          acc[mi][ni] = __builtin_amdgcn_mfma_f32_16x16x32_bf16(
              af[mi], bfr[ni], acc[mi][ni], 0, 0, 0);
    }
  }
#pragma unroll
  for (int ni = 0; ni < 2; ni++) {
    int n = n0 + w * 32 + ni * 16 + l15;
    float bv = g_gb1p[n];
#pragma unroll
    for (int mi = 0; mi < 4; mi++)
#pragma unroll
      for (int q = 0; q < 4; q++) {
        int row = r0 + mi * 16 + l4 * 4 + q;
        g_gh[(size_t)row * G_ + n] = f2bf(fmaxf(acc[mi][ni][q] + bv, 0.f));
      }
  }
}

// ---------------- gating softmax: gate = softmax(gh @ g_w2 + g_b2) ----------
__global__ __launch_bounds__(256) void k_gating_softmax(
    const float* __restrict__ gw2, const float* __restrict__ gb2) {
  int tid = threadIdx.x;
  int rl = tid >> 4, j = tid & 15;
  int row = blockIdx.x * 16 + rl;
  const u16* gr = g_gh + (size_t)row * G_;
  float acc = gb2[j];
  for (int k = 0; k < G_; k++) acc += bf2f(gr[k]) * gw2[k * 16 + j];
  float m = acc;
#pragma unroll
  for (int mm = 1; mm < 16; mm <<= 1) m = fmaxf(m, __shfl_xor(m, mm, 64));
  float e = expf(acc - m);
  float s = e;
#pragma unroll
  for (int mm = 1; mm < 16; mm <<= 1) s += __shfl_xor(s, mm, 64);
  g_gate[(size_t)row * 16 + j] = e / s;
}

// ---------------- fused expert chain ----------------------------------------
// XCD map: xcd owns row-blocks {xcd*8..xcd*8+7} x all 16 experts. Concurrent
// L2 set: A 2 MiB (L2-resident across all 16 kk re-reads) + 8 experts' W1
// kk-slices 2 MiB. Stage LDS is XOR-swizzled (linear dest, swizzled global
// source, swizzled fragment read) -> conflict-free ds_read_b128.
__global__ __launch_bounds__(256, 2) void k_chain(
    const float* __restrict__ eb2,  // [E_][G_]
    const float* __restrict__ w3,   // [E_][G_][2]
    const float* __restrict__ b3)   // [E_][2]
{
  constexpr int BM = 128, NT = 128, BK = 64;
  constexpr int C1LD = NT + 8;  // 272B row stride: ~2-way (free) on reads/writes
  __shared__ alignas(16) char pool[32768 + BM * C1LD * 2 + 2 * BM * 2 * 4];
  u16* A_st = (u16*)pool;                        // [128][64]
  u16* B_st = (u16*)(pool + 16384);              // [128][64]
  u16* C1 = (u16*)(pool + 32768);                // [128][136]
  float* oeac = (float*)(pool + 32768 + BM * C1LD * 2);  // [2][128][2]

  const int wg = blockIdx.x;          // 0..1023
  const int xcd = wg & 7;             // round-robin XCD assignment
  const int idx = wg >> 3;            // 0..127
  const int e = idx >> 3;             // 0..15 (8 experts per XCD batch)
  const int r0 = (xcd * 8 + (idx & 7)) * BM;  // row-blocks pinned per XCD

  const int tid = threadIdx.x;
  const int l = tid & 63, w = tid >> 6;
  const int wr = w >> 1, wc = w & 1;  // 2x2 wave grid
  const int l15 = l & 15, l4 = l >> 4, lx = l15 & 7;
  const int srow = tid >> 3;
  const int sk8s = (tid & 7) ^ ((tid >> 3) & 7);  // swizzled source col

  const u16* W1e = g_W1t + (size_t)e * H_ * D_;
  const u16* W2e = g_W2t + (size_t)e * G_ * H_;

  f32x4 zero4 = {0.f, 0.f, 0.f, 0.f};
  f32x4 acc2[4][8];
#pragma unroll
  for (int i = 0; i < 4; i++)
#pragma unroll
    for (int j = 0; j < 8; j++) acc2[i][j] = zero4;

  for (int kk = 0; kk < H_ / NT; kk++) {
    f32x4 acc1[4][4];
#pragma unroll
    for (int i = 0; i < 4; i++)
#pragma unroll
      for (int j = 0; j < 4; j++) acc1[i][j] = zero4;

    // ---- GEMM1: C1 = xhat[rows] @ W1'[:, kk*128 .. +128], K = 1024 ----
    for (int s = 0; s < D_ / BK; s++) {
      __syncthreads();
#pragma unroll
      for (int r = 0; r < 4; r++) {
        int row = r * 32 + srow;
        gld16(g_xhat + (size_t)(r0 + row) * D_ + s * BK + sk8s * 8,
              (char*)A_st + (r * 256 + (tid & 192)) * 16);
      }
#pragma unroll
      for (int r = 0; r < 4; r++) {
        int row = r * 32 + srow;
        gld16(W1e + (size_t)(kk * NT + row) * D_ + s * BK + sk8s * 8,
              (char*)B_st + (r * 256 + (tid & 192)) * 16);
      }
      __syncthreads();
#pragma unroll
      for (int t = 0; t < 2; t++) {
        bf16x8 af[4], bfr[4];
#pragma unroll
        for (int mi = 0; mi < 4; mi++)
          af[mi] = *(const bf16x8*)&A_st[(wr * 64 + mi * 16 + l15) * BK + ((t * 4 + l4) ^ lx) * 8];
#pragma unroll
        for (int ni = 0; ni < 4; ni++)
          bfr[ni] = *(const bf16x8*)&B_st[(wc * 64 + ni * 16 + l15) * BK + ((t * 4 + l4) ^ lx) * 8];
#pragma unroll
        for (int mi = 0; mi < 4; mi++)
#pragma unroll
          for (int ni = 0; ni < 4; ni++)
            acc1[mi][ni] = __builtin_amdgcn_mfma_f32_16x16x32_bf16(
                af[mi], bfr[ni], acc1[mi][ni], 0, 0, 0);
      }
    }
    // ---- bias + relu -> C1 (bf16, padded LDS) ----
    float bn[4];
#pragma unroll
    for (int ni = 0; ni < 4; ni++)
      bn[ni] = g_b1p[e * H_ + kk * NT + wc * 64 + ni * 16 + l15];
#pragma unroll
    for (int mi = 0; mi < 4; mi++)
#pragma unroll
      for (int ni = 0; ni < 4; ni++)
#pragma unroll
        for (int q = 0; q < 4; q++) {
          float v = fmaxf(acc1[mi][ni][q] + bn[ni], 0.f);
          C1[(wr * 64 + mi * 16 + l4 * 4 + q) * C1LD + wc * 64 + ni * 16 + l15] = f2bf(v);
        }
    __syncthreads();  // C1 visible; stage buffers now free for B2

    // ---- GEMM2: acc2 += relu-tile @ W2[kk*128 .. +128, :], K = 128 ----
#pragma unroll
    for (int k2 = 0; k2 < 2; k2++) {
#pragma unroll
      for (int r = 0; r < 8; r++) {
        int grow = r * 32 + srow;
        gld16(W2e + (size_t)grow * H_ + kk * NT + k2 * 64 + sk8s * 8,
              pool + (r * 256 + (tid & 192)) * 16);
      }
      __syncthreads();
      const u16* B2 = (const u16*)pool;  // [256][64]
#pragma unroll
      for (int t = 0; t < 2; t++) {
        bf16x8 a2[4];
#pragma unroll
        for (int mi = 0; mi < 4; mi++)
          a2[mi] = *(const bf16x8*)&C1[(wr * 64 + mi * 16 + l15) * C1LD + k2 * 64 + t * 32 + l4 * 8];
#pragma unroll
        for (int nj = 0; nj < 8; nj++) {
          bf16x8 b2 = *(const bf16x8*)&B2[(wc * 128 + nj * 16 + l15) * 64 + ((t * 4 + l4) ^ lx) * 8];
#pragma unroll
          for (int mi = 0; mi < 4; mi++)
            acc2[mi][nj] = __builtin_amdgcn_mfma_f32_16x16x32_bf16(
                a2[mi], b2, acc2[mi][nj], 0, 0, 0);
        }
      }
      __syncthreads();
    }
  }

  // ---- epilogue: oe = relu(h2 + b2) @ W3 ; oep = gate * (oe + b3) ----
  float w30[8], w31[8], bb[8];
#pragma unroll
  for (int nj = 0; nj < 8; nj++) {
    int g = wc * 128 + nj * 16 + l15;
    w30[nj] = w3[(e * G_ + g) * 2 + 0];
    w31[nj] = w3[(e * G_ + g) * 2 + 1];
    bb[nj] = eb2[e * G_ + g];
  }
#pragma unroll
  for (int mi = 0; mi < 4; mi++)
#pragma unroll
    for (int q = 0; q < 4; q++) {
      float s0 = 0.f, s1 = 0.f;
#pragma unroll
      for (int nj = 0; nj < 8; nj++) {
        float h = fmaxf(acc2[mi][nj][q] + bb[nj], 0.f);
        s0 += h * w30[nj];
        s1 += h * w31[nj];
      }
#pragma unroll
      for (int mm = 1; mm < 16; mm <<= 1) {
        s0 += __shfl_xor(s0, mm, 64);
        s1 += __shfl_xor(s1, mm, 64);
      }
      if (l15 == 0) {  // one writer per (wc, row): plain stores, no atomics
        int row = wr * 64 + mi * 16 + l4 * 4 + q;
        oeac[(wc * BM + row) * 2 + 0] = s0;
        oeac[(wc * BM + row) * 2 + 1] = s1;
      }
    }
  __syncthreads();
  if (tid < BM) {
    int row = tid;
    float gg = g_gate[(size_t)(r0 + row) * E_ + e];
    float o0 = oeac[row * 2 + 0] + oeac[(BM + row) * 2 + 0] + b3[e * 2 + 0];
    float o1 = oeac[row * 2 + 1] + oeac[(BM + row) * 2 + 1] + b3[e * 2 + 1];
    g_oep[((size_t)e * B_ + (r0 + row)) * 2 + 0] = gg * o0;
    g_oep[((size_t)e * B_ + (r0 + row)) * 2 + 1] = gg * o1;
  }
}

// ---------------- finalize: sum experts, split columns, softplus ------------
__global__ __launch_bounds__(256) void k_finalize(float* __restrict__ out) {
  int i = blockIdx.x * 256 + threadIdx.x;
  float m = 0.f, v = 0.f;
#pragma unroll
  for (int e = 0; e < E_; e++) {
    m += g_oep[((size_t)e * B_ + i) * 2 + 0];
    v += g_oep[((size_t)e * B_ + i) * 2 + 1];
  }
  float sp = (v > 20.f) ? v : log1pf(expf(v));
  out[i] = m;
  out[B_ + i] = sp + 1e-6f;
}

// ---------------------------------------------------------------------------
extern "C" void kernel_launch(void* const* d_in, const int* in_sizes, int n_in,
                              void* d_out, int out_size, void* d_ws, size_t ws_size,
                              hipStream_t stream) {
  const float* x    = (const float*)d_in[0];
  const float* glnw = (const float*)d_in[1];
  const float* glnb = (const float*)d_in[2];
  const float* gw1  = (const float*)d_in[3];
  const float* gb1  = (const float*)d_in[4];
  const float* gw2  = (const float*)d_in[5];
  const float* gb2  = (const float*)d_in[6];
  const float* elnw = (const float*)d_in[7];
  const float* elnb = (const float*)d_in[8];
  const float* ew1  = (const float*)d_in[9];
  const float* eb1  = (const float*)d_in[10];
  const float* ew2  = (const float*)d_in[11];
  const float* eb2  = (const float*)d_in[12];
  const float* ew3  = (const float*)d_in[13];
  const float* eb3  = (const float*)d_in[14];
  float* out = (float*)d_out;
  (void)d_ws; (void)ws_size;

  dim3 tb(32, 8);
  k_transpose_scale<<<dim3(H_ / 32, D_ / 32, E_), tb, 0, stream>>>(ew1, elnw, 0, D_, H_);
  k_transpose_scale<<<dim3(G_ / 32, H_ / 32, E_), tb, 0, stream>>>(ew2, nullptr, 1, H_, G_);
  k_transpose_scale<<<dim3(G_ / 32, D_ / 32, 1), tb, 0, stream>>>(gw1, glnw, 2, D_, G_);

  k_prep_bias<<<dim3(E_, H_ / 256, 4), 256, 0, stream>>>(ew1, elnb, eb1, 0, D_, H_, E_);
  k_prep_bias<<<dim3(1, 1, 4), 256, 0, stream>>>(gw1, glnb, gb1, 1, D_, G_, 1);
  k_combine_bias<<<(E_ * H_ + 255) / 256, 256, 0, stream>>>(0, E_ * H_);
  k_combine_bias<<<1, 256, 0, stream>>>(1, G_);

  k_layernorm<<<B_, 256, 0, stream>>>(x);
  k_gating_gemm<<<dim3(B_ / 64, G_ / 128), 256, 0, stream>>>();
  k_gating_softmax<<<B_ / 16, 256, 0, stream>>>(gw2, gb2);

  k_chain<<<dim3(B_ / 128 * E_), 256, 0, stream>>>(eb2, ew3, eb3);

  k_finalize<<<B_ / 256, 256, 0, stream>>>(out);
}